// Round 1
// baseline (86.990 us; speedup 1.0000x reference)
//
#include <hip/hip_runtime.h>
#include <math.h>

// Problem: KANLayer — out[b,o] = sum_i C[i,o]*(sum_k basis_k(x[b,i])*W[i,o,k] + bias[i,o])
// Collapses to GEMM: out = feats[4096 x 1152] * Weff[1152 x 128] + bterm[o]
//   feats[b, i*9+k] = basis_k(x[b,i])          (bf16)
//   Weff[i*9+k, o]  = W[i,o,k]*C[i,o]          (bf16, stored transposed as BT[o][kk])
//   bterm[o]        = sum_i bias[i,o]*C[i,o]   (f32)

#define DIN   128
#define DOUT  128
#define NB    9
#define KK    (DIN * NB)   // 1152
#define BATCH 4096

typedef __bf16 bf16x8 __attribute__((ext_vector_type(8)));
typedef float  f32x4  __attribute__((ext_vector_type(4)));

// ---------------- kernel 1: basis expansion x -> feats (bf16) ----------------
// one block per batch row; 128 threads each handle one x element (9 outputs),
// staged in LDS so the global write is coalesced 4B stores.
__global__ __launch_bounds__(128) void feats_kernel(const float* __restrict__ x,
                                                    __bf16* __restrict__ feats) {
    __shared__ __bf16 row[KK];           // 2304 B
    const int b = blockIdx.x;
    const int i = threadIdx.x;           // 0..127
    const float v  = x[b * DIN + i];
    const float av = fabsf(v);

    float f[NB];
    f[0] = v;
    f[1] = v * v;
    f[2] = v * v * v;
    f[3] = __expf(v);
    f[4] = __logf(av + 1.0f);
    f[5] = __builtin_sqrtf(av);
    f[6] = tanhf(v);
    f[7] = __sinf(v);
    f[8] = av;

    #pragma unroll
    for (int k = 0; k < NB; ++k) row[i * NB + k] = (__bf16)f[k];
    __syncthreads();

    // copy 2304 B = 576 dwords out, coalesced
    const unsigned int* src = (const unsigned int*)row;
    unsigned int* dst = (unsigned int*)feats + (size_t)b * (KK / 2);
    for (int j = i; j < KK / 2; j += 128) dst[j] = src[j];
}

// ---------------- kernel 2: fold W*C -> BT (bf16, transposed) + bterm --------
// idx = o*1152 + i*9 + k  (coalesced writes to BT)
__global__ __launch_bounds__(256) void fold_kernel(const float* __restrict__ W,
                                                   const float* __restrict__ bias,
                                                   const float* __restrict__ C,
                                                   __bf16* __restrict__ BT,
                                                   float* __restrict__ bterm) {
    const int idx = blockIdx.x * 256 + threadIdx.x;   // 0 .. 147455
    const int o = idx / KK;
    const int r = idx - o * KK;
    const int i = r / NB;
    const int k = r - i * NB;
    const float w = W[((size_t)i * DOUT + o) * NB + k];
    const float c = C[i * DOUT + o];
    BT[idx] = (__bf16)(w * c);

    if (blockIdx.x == 0 && threadIdx.x < DOUT) {
        const int oo = threadIdx.x;
        float s = 0.0f;
        for (int ii = 0; ii < DIN; ++ii)
            s += bias[ii * DOUT + oo] * C[ii * DOUT + oo];
        bterm[oo] = s;
    }
}

// ---------------- kernel 3: MFMA GEMM ----------------------------------------
// block = 512 threads = 8 waves; block handles 16 batch rows x all 128 cols,
// wave w handles the 16x16 tile at cols w*16. Fragments loaded directly from
// global (L1/L2-resident working set, no LDS staging needed at this size).
// Layouts (HW-verified, guide §3): A-frag A[m=lane&15][k=quad*8+j],
// B-frag  BT[n=lane&15][k=quad*8+j],  C/D col=lane&15 row=quad*4+reg.
__global__ __launch_bounds__(512, 1) void gemm_kernel(const __bf16* __restrict__ A,
                                                      const __bf16* __restrict__ BT,
                                                      const float* __restrict__ bterm,
                                                      float* __restrict__ out) {
    const int lane = threadIdx.x & 63;
    const int wave = threadIdx.x >> 6;   // 0..7 -> col tile
    const int m    = lane & 15;
    const int quad = lane >> 4;
    const int row0 = blockIdx.x << 4;    // 16 rows per block
    const int col0 = wave << 4;

    const bf16x8* Ap = (const bf16x8*)(A  + (size_t)(row0 + m) * KK + quad * 8);
    const bf16x8* Bp = (const bf16x8*)(BT + (size_t)(col0 + m) * KK + quad * 8);

    f32x4 acc = {0.0f, 0.0f, 0.0f, 0.0f};

    #pragma unroll 6
    for (int kc = 0; kc < KK / 32; ++kc) {     // 36 iters
        bf16x8 a = Ap[kc * 4];                 // kc*32 elements
        bf16x8 b = Bp[kc * 4];
        acc = __builtin_amdgcn_mfma_f32_16x16x32_bf16(a, b, acc, 0, 0, 0);
    }

    const float bt = bterm[col0 + m];
    float* op = out + (size_t)(row0 + quad * 4) * DOUT + col0 + m;
    #pragma unroll
    for (int r = 0; r < 4; ++r) op[(size_t)r * DOUT] = acc[r] + bt;
}

// ---------------- launcher ---------------------------------------------------
extern "C" void kernel_launch(void* const* d_in, const int* in_sizes, int n_in,
                              void* d_out, int out_size, void* d_ws, size_t ws_size,
                              hipStream_t stream) {
    const float* x    = (const float*)d_in[0];   // [4096,128]
    const float* W    = (const float*)d_in[1];   // [128,128,9]
    const float* bias = (const float*)d_in[2];   // [128,128]
    const float* C    = (const float*)d_in[3];   // [128,128]
    float* out = (float*)d_out;                  // [4096,128]

    // workspace layout
    char* ws = (char*)d_ws;
    __bf16* feats = (__bf16*)ws;                                   // 4096*1152*2 = 9,437,184 B
    __bf16* BT    = (__bf16*)(ws + (size_t)BATCH * KK * 2);        // 128*1152*2  =   294,912 B
    float*  bterm = (float*)(ws + (size_t)BATCH * KK * 2 + (size_t)DOUT * KK * 2); // 512 B

    feats_kernel<<<BATCH, 128, 0, stream>>>(x, feats);
    fold_kernel<<<(DOUT * KK) / 256, 256, 0, stream>>>(W, bias, C, BT, bterm);
    gemm_kernel<<<BATCH / 16, 512, 0, stream>>>(feats, BT, bterm, out);
}

// Round 2
// 74.509 us; speedup vs baseline: 1.1675x; 1.1675x over previous
//
#include <hip/hip_runtime.h>
#include <math.h>

// KANLayer: out[b,o] = sum_i C[i,o]*(sum_k basis_k(x[b,i])*W[i,o,k] + bias[i,o])
// = GEMM: out = feats[4096 x 1152] * Weff[1152 x 128] + bterm[o]
// R2: feats fused into the GEMM kernel (basis -> LDS -> MFMA A-frags);
//     removes the 9.4 MB x2 HBM round-trip and one launch vs R1.

#define DIN   128
#define DOUT  128
#define NB    9
#define KK    (DIN * NB)    // 1152
#define BATCH 4096
#define ROWS  16            // batch rows per block
#define APAD  8             // +8 bf16 -> row stride 580 dwords (=4 mod 32, 2-way free)
#define ASTR  (KK + APAD)   // 1160

typedef __bf16 bf16x8 __attribute__((ext_vector_type(8)));
typedef float  f32x4  __attribute__((ext_vector_type(4)));

// ---------------- kernel 1: fold W*C -> BT (bf16, transposed) + bterm --------
__global__ __launch_bounds__(256) void fold_kernel(const float* __restrict__ W,
                                                   const float* __restrict__ bias,
                                                   const float* __restrict__ C,
                                                   __bf16* __restrict__ BT,
                                                   float* __restrict__ bterm) {
    const int idx = blockIdx.x * 256 + threadIdx.x;   // 0 .. 147455
    const int o = idx / KK;
    const int r = idx - o * KK;
    const int i = r / NB;
    const int k = r - i * NB;
    const float w = W[((size_t)i * DOUT + o) * NB + k];
    const float c = C[i * DOUT + o];
    BT[idx] = (__bf16)(w * c);

    if (blockIdx.x == 0 && threadIdx.x < DOUT) {
        const int oo = threadIdx.x;
        float s = 0.0f;
        for (int ii = 0; ii < DIN; ++ii)
            s += bias[ii * DOUT + oo] * C[ii * DOUT + oo];
        bterm[oo] = s;
    }
}

// ---------------- kernel 2: fused basis expansion + MFMA GEMM ----------------
// 256 blocks x 512 threads (8 waves). Block: 16 batch rows x all 128 cols.
// Stage 1: 2048 x-values -> 9 basis funcs each -> LDS A[16][1160] bf16.
// Stage 2: wave w computes the 16x16 tile at cols w*16; A-frags from LDS,
//          B-frags from global (BT = 294 KB, L2-resident across all blocks).
// Layouts (HW-verified, guide §3): A-frag A[m=lane&15][k=quad*8+j],
// B-frag BT[n=lane&15][k=quad*8+j], C/D col=lane&15 row=quad*4+reg.
__global__ __launch_bounds__(512, 1) void fused_kernel(const float* __restrict__ x,
                                                       const __bf16* __restrict__ BT,
                                                       const float* __restrict__ bterm,
                                                       float* __restrict__ out) {
    __shared__ __bf16 As[ROWS * ASTR];   // 37120 B
    const int t    = threadIdx.x;
    const int row0 = blockIdx.x * ROWS;

    // ---- stage 1: basis expansion into LDS ----
    for (int e = t; e < ROWS * DIN; e += 512) {
        const int r = e >> 7;            // row within tile
        const int i = e & 127;           // din index
        const float v  = x[(size_t)(row0 + r) * DIN + i];
        const float av = fabsf(v);
        float f[NB];
        f[0] = v;
        f[1] = v * v;
        f[2] = v * v * v;
        f[3] = __expf(v);
        f[4] = __logf(av + 1.0f);
        f[5] = __builtin_sqrtf(av);
        f[6] = tanhf(v);
        f[7] = __sinf(v);
        f[8] = av;
        __bf16* dst = &As[r * ASTR + i * NB];
        #pragma unroll
        for (int k = 0; k < NB; ++k) dst[k] = (__bf16)f[k];
    }
    __syncthreads();

    // ---- stage 2: MFMA ----
    const int lane = t & 63;
    const int wave = t >> 6;             // 0..7 -> col tile
    const int m    = lane & 15;
    const int quad = lane >> 4;
    const int col0 = wave << 4;

    const __bf16* Ap = &As[m * ASTR + quad * 8];
    const __bf16* Bp = BT + (size_t)(col0 + m) * KK + quad * 8;

    f32x4 acc = {0.0f, 0.0f, 0.0f, 0.0f};

    #pragma unroll 6
    for (int kc = 0; kc < KK / 32; ++kc) {   // 36 iters
        bf16x8 a = *(const bf16x8*)(Ap + kc * 32);
        bf16x8 b = *(const bf16x8*)(Bp + kc * 32);
        acc = __builtin_amdgcn_mfma_f32_16x16x32_bf16(a, b, acc, 0, 0, 0);
    }

    const float bt = bterm[col0 + m];
    float* op = out + (size_t)(row0 + quad * 4) * DOUT + col0 + m;
    #pragma unroll
    for (int r = 0; r < 4; ++r) op[(size_t)r * DOUT] = acc[r] + bt;
}

// ---------------- launcher ---------------------------------------------------
extern "C" void kernel_launch(void* const* d_in, const int* in_sizes, int n_in,
                              void* d_out, int out_size, void* d_ws, size_t ws_size,
                              hipStream_t stream) {
    const float* x    = (const float*)d_in[0];   // [4096,128]
    const float* W    = (const float*)d_in[1];   // [128,128,9]
    const float* bias = (const float*)d_in[2];   // [128,128]
    const float* C    = (const float*)d_in[3];   // [128,128]
    float* out = (float*)d_out;                  // [4096,128]

    char* ws = (char*)d_ws;
    __bf16* BT    = (__bf16*)ws;                              // 128*1152*2 = 294,912 B
    float*  bterm = (float*)(ws + (size_t)DOUT * KK * 2);     // 512 B

    fold_kernel<<<(DOUT * KK) / 256, 256, 0, stream>>>(W, bias, C, BT, bterm);
    fused_kernel<<<BATCH / ROWS, 512, 0, stream>>>(x, BT, bterm, out);
}